// Round 2
// baseline (135.325 us; speedup 1.0000x reference)
//
#include <hip/hip_runtime.h>

// Problem constants
#define N_FILTERS 1024
#define B_TOTAL   1024
#define IMG       64            // H = W = 64
#define PAD_DIM   70            // 64 + 2*3 padded image side
// Xt layout in d_ws: fp16 [8 bg][PAD_DIM*PAD_DIM pixels][128 batches]  (10 MB).
// bg-major: each XCD's hot slice (4900 px * 256 B = 1.25 MB) is CONTIGUOUS and
// pixel stride is 256 B, so the 10 column loads per window row fold into
// 13-bit immediate offsets (wc*256 <= 2304).
// Window consumed per filter: padded rows i..i+9, cols j..j+9 (pool floor mode
// discards conv row/col 6, so only a 10x10 slab of the 11x11 window is read).

// ---------------- prep 1: zero the padded border of Xt (compact grid) ----------------
__global__ void zero_border_kernel(_Float16* __restrict__ Xt) {
    int bid = blockIdx.x;                 // 0..803
    int r, c;
    if (bid < 420) {
        int r6 = bid / 70;                // 0..5
        c = bid - r6 * 70;
        r = (r6 < 3) ? r6 : r6 + 64;      // rows 0,1,2,67,68,69
    } else {
        int t = bid - 420;
        r = 3 + t / 6;
        int k = t - (t / 6) * 6;          // 0..5
        c = (k < 3) ? k : k + 64;         // cols 0,1,2,67,68,69
    }
    const size_t pp = (size_t)r * PAD_DIM + c;
    const int bg = threadIdx.x >> 5, l = threadIdx.x & 31;
    unsigned long long* q = (unsigned long long*)Xt
        + (size_t)bg * (4900ull * 32) + pp * 32 + l;
    *q = 0ull;
}

// ---------------- prep 2: transpose X [1024 b][4096 p] -> Xt fp16 bg-major ----------------
__global__ __launch_bounds__(256) void transpose_kernel(
    const float* __restrict__ X, _Float16* __restrict__ Xt)
{
    __shared__ float T[64 * 65];         // [b_local][p_local], stride 65 kills conflicts
    const int pt = blockIdx.x & 63;      // pixel tile (64 pixels)
    const int bt = blockIdx.x >> 6;      // batch tile (64 batches)
    const int tx = threadIdx.x & 63, ty = threadIdx.x >> 6;

    #pragma unroll
    for (int pass = 0; pass < 16; ++pass) {
        int bl = pass * 4 + ty;          // lanes: consecutive pixels -> coalesced read
        T[bl * 65 + tx] = X[(size_t)(bt * 64 + bl) * 4096 + pt * 64 + tx];
    }
    __syncthreads();
    #pragma unroll
    for (int pass = 0; pass < 16; ++pass) {
        int pl = pass * 4 + ty;
        int p  = pt * 64 + pl;
        int r  = p >> 6, c = p & 63;
        // batch b = bt*64+tx -> bg = bt>>1, inner = (bt&1)*64 + tx
        Xt[((size_t)(bt >> 1) * 4900 + (size_t)(r + 3) * PAD_DIM + (c + 3)) * 128
           + (bt & 1) * 64 + tx] = (_Float16)T[tx * 65 + pl];
    }
}

// ---------------- main: ONE batch per lane, early pool-fold, no spills ----------------
// Block = 4 waves = 4 filters, 64 batches. Grid 4096: xcd = bid&7 pins the bg
// slice; per-XCD hot data = 1.25 MB in L2. acc[36] f32 with early fold: conv
// row y completes at window row y+4, folds into pmax[4] and dies -> peak live
// acc = 30 regs; total live ~55 -> honest 64-80 VGPR, 6-8 blocks/CU.

#define LOAD_ROW(buf, WR) do {                                                  \
    const _Float16* rp_ = Xg + (size_t)((si + (WR)) * PAD_DIM + sj) * 128;      \
    _Pragma("unroll")                                                           \
    for (int wc = 0; wc < 10; ++wc) buf[wc] = rp_[wc * 128];                    \
} while (0)

#define COMPUTE_ROW(buf, WR) do {                                               \
    float in_[10];                                                              \
    _Pragma("unroll")                                                           \
    for (int wc = 0; wc < 10; ++wc) in_[wc] = (float)buf[wc];                   \
    _Pragma("unroll")                                                           \
    for (int y = 0; y < 6; ++y) {                                               \
        if (y >= (((WR) > 4) ? ((WR) - 4) : 0) && y <= (((WR) < 5) ? (WR) : 5)) { \
            const int rr = (WR) - y;                                            \
            _Pragma("unroll")                                                   \
            for (int x = 0; x < 6; ++x) {                                       \
                float s_ = acc[y * 6 + x];                                      \
                _Pragma("unroll")                                               \
                for (int c = 0; c < 5; ++c)                                     \
                    s_ = fmaf(wk[rr * 5 + c], in_[x + c], s_);                  \
                acc[y * 6 + x] = s_;                                            \
            }                                                                   \
        }                                                                       \
    }                                                                           \
    if ((WR) >= 4) {                                                            \
        const int fy = (WR) - 4;                                                \
        _Pragma("unroll")                                                       \
        for (int px = 0; px < 2; ++px) {                                        \
            float m_ = fmaxf(fmaxf(acc[fy * 6 + 3 * px],                        \
                                   acc[fy * 6 + 3 * px + 1]),                   \
                             acc[fy * 6 + 3 * px + 2]);                         \
            const int pi = ((fy >= 3) ? 2 : 0) + px;                            \
            pmax[pi] = fmaxf(pmax[pi], m_);                                     \
        }                                                                       \
    }                                                                           \
} while (0)

__global__ __launch_bounds__(256, 6) void filters_main(
    const _Float16* __restrict__ Xt,   // [8 bg][4900 px][128 b] fp16
    const float*    __restrict__ W,    // [F][25]
    const float*    __restrict__ bias, // [F]
    const int*      __restrict__ pos,  // [F][2]
    float4*         __restrict__ out4) // [B][1024 float4]  (= [B][F*4] floats)
{
    const int t    = threadIdx.x;
    const int lane = t & 63;
    const int w    = t >> 6;                       // wave id 0..3
    const int bid  = blockIdx.x;
    const int xcd  = bid & 7;                      // XCD pin -> bg slice
    const int m    = bid >> 3;                     // 0..511
    const int bgr  = xcd * 2 + (m & 1);            // batch group of 64, 0..15
    const int fg   = m >> 1;                       // filter group, 0..255

    const int f  = fg * 4 + w;
    const int sf = __builtin_amdgcn_readfirstlane(f);
    const int si = __builtin_amdgcn_readfirstlane(pos[2 * sf]);       // row i, 0..59
    const int sj = __builtin_amdgcn_readfirstlane(pos[2 * sf + 1]);   // col j, 0..59

    float wk[25];
    const float* wp = W + sf * 25;                 // scalar address -> s_load into SGPRs
    #pragma unroll
    for (int k = 0; k < 25; ++k) wk[k] = wp[k];

    // lane's batch within the bg slice: half = bgr&1 selects 64 of the 128
    const _Float16* Xg = Xt + (size_t)xcd * (4900ull * 128) + (bgr & 1) * 64 + lane;

    float acc[36];
    #pragma unroll
    for (int k = 0; k < 36; ++k) acc[k] = 0.0f;
    float pmax[4];
    #pragma unroll
    for (int k = 0; k < 4; ++k) pmax[k] = -__builtin_inff();

    _Float16 bufA[10], bufB[10];
    LOAD_ROW(bufA, 0);
    LOAD_ROW(bufB, 1);  COMPUTE_ROW(bufA, 0);
    LOAD_ROW(bufA, 2);  COMPUTE_ROW(bufB, 1);
    LOAD_ROW(bufB, 3);  COMPUTE_ROW(bufA, 2);
    LOAD_ROW(bufA, 4);  COMPUTE_ROW(bufB, 3);
    LOAD_ROW(bufB, 5);  COMPUTE_ROW(bufA, 4);
    LOAD_ROW(bufA, 6);  COMPUTE_ROW(bufB, 5);
    LOAD_ROW(bufB, 7);  COMPUTE_ROW(bufA, 6);
    LOAD_ROW(bufA, 8);  COMPUTE_ROW(bufB, 7);
    LOAD_ROW(bufB, 9);  COMPUTE_ROW(bufA, 8);
                        COMPUTE_ROW(bufB, 9);

    // ---- epilogue: merge 4 waves' 16B outputs into full 64B stores via LDS ----
    const float bv = bias[sf];
    __shared__ float S[4][65][4];                  // [wave/filter-sub][batch][4], padded
    #pragma unroll
    for (int k = 0; k < 4; ++k) S[w][lane][k] = pmax[k] + bv;
    __syncthreads();

    // thread t -> batch row r = t>>2, filter-sub q = t&3; 4 consecutive lanes
    // write one contiguous, aligned 64B line: out[b][fg*16 .. fg*16+15].
    const int r = t >> 2, q = t & 3;
    float4 val;
    val.x = S[q][r][0];
    val.y = S[q][r][1];
    val.z = S[q][r][2];
    val.w = S[q][r][3];
    out4[(size_t)(bgr * 64 + r) * 1024 + (fg * 4 + q)] = val;
}

extern "C" void kernel_launch(void* const* d_in, const int* in_sizes, int n_in,
                              void* d_out, int out_size, void* d_ws, size_t ws_size,
                              hipStream_t stream) {
    const float* X    = (const float*)d_in[0];
    const float* W    = (const float*)d_in[1];
    const float* bias = (const float*)d_in[2];
    const int*   pos  = (const int*)d_in[3];
    float4* out4 = (float4*)d_out;
    _Float16* Xt = (_Float16*)d_ws;        // 8*4900*128 fp16 = 10 MB

    zero_border_kernel<<<804, 256, 0, stream>>>(Xt);
    transpose_kernel<<<1024, 256, 0, stream>>>(X, Xt);
    filters_main<<<4096, 256, 0, stream>>>(Xt, W, bias, pos, out4);
}

// Round 3
// 109.975 us; speedup vs baseline: 1.2305x; 1.2305x over previous
//
#include <hip/hip_runtime.h>

// Problem constants
#define N_FILTERS 1024
#define B_TOTAL   1024
#define IMG       64            // H = W = 64
#define PAD_DIM   70            // 64 + 2*3 padded image side
// Xt layout in d_ws: fp16 [8 bg][PAD_DIM*PAD_DIM pixels][128 batches]  (10 MB).
// bg-major: each XCD's hot slice (4900 px * 256 B = 1.25 MB) is CONTIGUOUS and
// pixel stride is 256 B, so the 10 column loads per window row fold into
// 13-bit immediate offsets (wc*256 <= 2304).
// Window consumed per filter: padded rows i..i+9, cols j..j+9 (pool floor mode
// discards conv row/col 6, so only a 10x10 slab of the 11x11 window is read).
//
// LESSON (rounds 1-2): __launch_bounds__ min-waves arg on gfx950 caps VGPRs
// ~2x harder than 512/N -> (256,4) gave 64 VGPR, (256,6) gave 40 VGPR, both
// spilled 60-145 MB to scratch (WRITE_SIZE 78/160 MB vs 16 MB true output).
// Fix: no min-waves arg; live set ~66 regs -> allocator picks ~80-100, no
// spill, still 5+ waves/SIMD.

// ---------------- prep 1: zero the padded border of Xt (compact grid) ----------------
__global__ void zero_border_kernel(_Float16* __restrict__ Xt) {
    int bid = blockIdx.x;                 // 0..803
    int r, c;
    if (bid < 420) {
        int r6 = bid / 70;                // 0..5
        c = bid - r6 * 70;
        r = (r6 < 3) ? r6 : r6 + 64;      // rows 0,1,2,67,68,69
    } else {
        int t = bid - 420;
        r = 3 + t / 6;
        int k = t - (t / 6) * 6;          // 0..5
        c = (k < 3) ? k : k + 64;         // cols 0,1,2,67,68,69
    }
    const size_t pp = (size_t)r * PAD_DIM + c;
    const int bg = threadIdx.x >> 5, l = threadIdx.x & 31;
    unsigned long long* q = (unsigned long long*)Xt
        + (size_t)bg * (4900ull * 32) + pp * 32 + l;
    *q = 0ull;
}

// ---------------- prep 2: transpose X [1024 b][4096 p] -> Xt fp16 bg-major ----------------
__global__ __launch_bounds__(256) void transpose_kernel(
    const float* __restrict__ X, _Float16* __restrict__ Xt)
{
    __shared__ float T[64 * 65];         // [b_local][p_local], stride 65 kills conflicts
    const int pt = blockIdx.x & 63;      // pixel tile (64 pixels)
    const int bt = blockIdx.x >> 6;      // batch tile (64 batches)
    const int tx = threadIdx.x & 63, ty = threadIdx.x >> 6;

    #pragma unroll
    for (int pass = 0; pass < 16; ++pass) {
        int bl = pass * 4 + ty;          // lanes: consecutive pixels -> coalesced read
        T[bl * 65 + tx] = X[(size_t)(bt * 64 + bl) * 4096 + pt * 64 + tx];
    }
    __syncthreads();
    #pragma unroll
    for (int pass = 0; pass < 16; ++pass) {
        int pl = pass * 4 + ty;
        int p  = pt * 64 + pl;
        int r  = p >> 6, c = p & 63;
        // batch b = bt*64+tx -> bg = bt>>1, inner = (bt&1)*64 + tx
        Xt[((size_t)(bt >> 1) * 4900 + (size_t)(r + 3) * PAD_DIM + (c + 3)) * 128
           + (bt & 1) * 64 + tx] = (_Float16)T[tx * 65 + pl];
    }
}

// ---------------- main: ONE batch per lane, early pool-fold, no spills ----------------
// Block = 4 waves = 4 filters, 64 batches. Grid 4096: xcd = bid&7 pins the bg
// slice; per-XCD hot data = 1.25 MB in L2. acc[36] f32 with early fold: conv
// row y completes at window row y+4, folds into pmax[4] and dies.

#define LOAD_ROW(buf, WR) do {                                                  \
    const _Float16* rp_ = Xg + (size_t)((si + (WR)) * PAD_DIM + sj) * 128;      \
    _Pragma("unroll")                                                           \
    for (int wc = 0; wc < 10; ++wc) buf[wc] = rp_[wc * 128];                    \
} while (0)

#define COMPUTE_ROW(buf, WR) do {                                               \
    float in_[10];                                                              \
    _Pragma("unroll")                                                           \
    for (int wc = 0; wc < 10; ++wc) in_[wc] = (float)buf[wc];                   \
    _Pragma("unroll")                                                           \
    for (int y = 0; y < 6; ++y) {                                               \
        if (y >= (((WR) > 4) ? ((WR) - 4) : 0) && y <= (((WR) < 5) ? (WR) : 5)) { \
            const int rr = (WR) - y;                                            \
            _Pragma("unroll")                                                   \
            for (int x = 0; x < 6; ++x) {                                       \
                float s_ = acc[y * 6 + x];                                      \
                _Pragma("unroll")                                               \
                for (int c = 0; c < 5; ++c)                                     \
                    s_ = fmaf(wk[rr * 5 + c], in_[x + c], s_);                  \
                acc[y * 6 + x] = s_;                                            \
            }                                                                   \
        }                                                                       \
    }                                                                           \
    if ((WR) >= 4) {                                                            \
        const int fy = (WR) - 4;                                                \
        _Pragma("unroll")                                                       \
        for (int px = 0; px < 2; ++px) {                                        \
            float m_ = fmaxf(fmaxf(acc[fy * 6 + 3 * px],                        \
                                   acc[fy * 6 + 3 * px + 1]),                   \
                             acc[fy * 6 + 3 * px + 2]);                         \
            const int pi = ((fy >= 3) ? 2 : 0) + px;                            \
            pmax[pi] = fmaxf(pmax[pi], m_);                                     \
        }                                                                       \
    }                                                                           \
} while (0)

__global__ __launch_bounds__(256) void filters_main(
    const _Float16* __restrict__ Xt,   // [8 bg][4900 px][128 b] fp16
    const float*    __restrict__ W,    // [F][25]
    const float*    __restrict__ bias, // [F]
    const int*      __restrict__ pos,  // [F][2]
    float4*         __restrict__ out4) // [B][1024 float4]  (= [B][F*4] floats)
{
    const int t    = threadIdx.x;
    const int lane = t & 63;
    const int w    = t >> 6;                       // wave id 0..3
    const int bid  = blockIdx.x;
    const int xcd  = bid & 7;                      // XCD pin -> bg slice
    const int m    = bid >> 3;                     // 0..511
    const int bgr  = xcd * 2 + (m & 1);            // batch group of 64, 0..15
    const int fg   = m >> 1;                       // filter group, 0..255

    const int f  = fg * 4 + w;
    const int sf = __builtin_amdgcn_readfirstlane(f);
    const int si = __builtin_amdgcn_readfirstlane(pos[2 * sf]);       // row i, 0..59
    const int sj = __builtin_amdgcn_readfirstlane(pos[2 * sf + 1]);   // col j, 0..59

    float wk[25];
    const float* wp = W + sf * 25;                 // scalar address -> s_load into SGPRs
    #pragma unroll
    for (int k = 0; k < 25; ++k) wk[k] = wp[k];

    // lane's batch within the bg slice: half = bgr&1 selects 64 of the 128
    const _Float16* Xg = Xt + (size_t)xcd * (4900ull * 128) + (bgr & 1) * 64 + lane;

    float acc[36];
    #pragma unroll
    for (int k = 0; k < 36; ++k) acc[k] = 0.0f;
    float pmax[4];
    #pragma unroll
    for (int k = 0; k < 4; ++k) pmax[k] = -__builtin_inff();

    _Float16 bufA[10], bufB[10];
    LOAD_ROW(bufA, 0);
    LOAD_ROW(bufB, 1);  COMPUTE_ROW(bufA, 0);
    LOAD_ROW(bufA, 2);  COMPUTE_ROW(bufB, 1);
    LOAD_ROW(bufB, 3);  COMPUTE_ROW(bufA, 2);
    LOAD_ROW(bufA, 4);  COMPUTE_ROW(bufB, 3);
    LOAD_ROW(bufB, 5);  COMPUTE_ROW(bufA, 4);
    LOAD_ROW(bufA, 6);  COMPUTE_ROW(bufB, 5);
    LOAD_ROW(bufB, 7);  COMPUTE_ROW(bufA, 6);
    LOAD_ROW(bufA, 8);  COMPUTE_ROW(bufB, 7);
    LOAD_ROW(bufB, 9);  COMPUTE_ROW(bufA, 8);
                        COMPUTE_ROW(bufB, 9);

    // ---- epilogue: merge 4 waves' 16B outputs into full 64B stores via LDS ----
    const float bv = bias[sf];
    __shared__ float S[4][64][5];                  // inner stride 5 -> no bank conflicts
    #pragma unroll
    for (int k = 0; k < 4; ++k) S[w][lane][k] = pmax[k] + bv;
    __syncthreads();

    // thread t -> batch row r = t>>2, filter-sub q = t&3; 4 consecutive lanes
    // write one contiguous, aligned 64B line: out[b][fg*16 .. fg*16+15].
    const int r = t >> 2, q = t & 3;
    float4 val;
    val.x = S[q][r][0];
    val.y = S[q][r][1];
    val.z = S[q][r][2];
    val.w = S[q][r][3];
    out4[(size_t)(bgr * 64 + r) * 1024 + (fg * 4 + q)] = val;
}

extern "C" void kernel_launch(void* const* d_in, const int* in_sizes, int n_in,
                              void* d_out, int out_size, void* d_ws, size_t ws_size,
                              hipStream_t stream) {
    const float* X    = (const float*)d_in[0];
    const float* W    = (const float*)d_in[1];
    const float* bias = (const float*)d_in[2];
    const int*   pos  = (const int*)d_in[3];
    float4* out4 = (float4*)d_out;
    _Float16* Xt = (_Float16*)d_ws;        // 8*4900*128 fp16 = 10 MB

    zero_border_kernel<<<804, 256, 0, stream>>>(Xt);
    transpose_kernel<<<1024, 256, 0, stream>>>(X, Xt);
    filters_main<<<4096, 256, 0, stream>>>(Xt, W, bias, pos, out4);
}

// Round 5
// 97.551 us; speedup vs baseline: 1.3872x; 1.1274x over previous
//
#include <hip/hip_runtime.h>

// Problem constants
#define N_FILTERS 1024
#define B_TOTAL   1024
#define IMG       64            // H = W = 64
#define PAD_DIM   70            // 64 + 2*3 padded image side
// Xt layout in d_ws: fp16 [8 bg][PAD_DIM*PAD_DIM pixels][128 batches]  (10 MB).
// bg-major: each XCD's hot slice (4900 px * 256 B = 1.25 MB) is CONTIGUOUS and
// pixel stride is 256 B, so the 10 column loads per window row fold into
// 13-bit immediate offsets (wc*256 <= 2304).
// Window consumed per filter: padded rows i..i+9, cols j..j+9 (pool floor mode
// discards conv row/col 6, so only a 10x10 slab of the 11x11 window is read).
//
// LESSONS:
//  r1-r2: __launch_bounds__ min-waves on gfx950 caps VGPRs ~2x harder than
//         512/N -> (256,4)=64 VGPR, (256,6)=40 VGPR, 60-145 MB scratch spills.
//         Fix: no min-waves arg, let the allocator pick.
//  r3:    one-batch-per-lane removed the spills but also removed round-0's
//         v_pk_fma_f32 (2 FMA/instr). This round: packed math AND no spills,
//         via early pool-fold + lazy acc init (peak live acc rows = 5).
//  r4:    container failed twice (infra); code audit found no OOB/hang -> rerun.
//  fixed: harness re-poisons the 256 MiB workspace every iter (~45 us fill
//         inside the timed window). Controllable budget = dur - 45.

typedef _Float16 half2_t __attribute__((ext_vector_type(2)));
typedef float    fvec2  __attribute__((ext_vector_type(2)));

// ---------------- prep: transpose + border-zero fused in one launch ----------------
// Blocks 0..1023: transpose X [1024 b][4096 p] -> Xt fp16 bg-major.
// Blocks 1024..1827: zero one border pixel each (804 px * 8 bg * 256 B).
__global__ __launch_bounds__(256) void prep_kernel(
    const float* __restrict__ X, _Float16* __restrict__ Xt)
{
    const int bid = blockIdx.x;
    if (bid >= 1024) {
        int pb = bid - 1024;              // 0..803
        int r, c;
        if (pb < 420) {
            int r6 = pb / 70;             // 0..5
            c = pb - r6 * 70;
            r = (r6 < 3) ? r6 : r6 + 64;  // rows 0,1,2,67,68,69
        } else {
            int q = pb - 420;
            r = 3 + q / 6;
            int k = q - (q / 6) * 6;      // 0..5
            c = (k < 3) ? k : k + 64;     // cols 0,1,2,67,68,69
        }
        const size_t pp = (size_t)r * PAD_DIM + c;
        const int bg = threadIdx.x >> 5, l = threadIdx.x & 31;
        unsigned long long* qp = (unsigned long long*)Xt
            + (size_t)bg * (4900ull * 32) + pp * 32 + l;
        *qp = 0ull;
        return;
    }

    __shared__ float T[64 * 65];         // [b_local][p_local], stride 65 kills conflicts
    const int pt = bid & 63;             // pixel tile (64 pixels)
    const int bt = bid >> 6;             // batch tile (64 batches)
    const int tx = threadIdx.x & 63, ty = threadIdx.x >> 6;

    #pragma unroll
    for (int pass = 0; pass < 16; ++pass) {
        int bl = pass * 4 + ty;          // lanes: consecutive pixels -> coalesced read
        T[bl * 65 + tx] = X[(size_t)(bt * 64 + bl) * 4096 + pt * 64 + tx];
    }
    __syncthreads();

    // write half2 (two consecutive batches) per lane -> dword stores, 8 passes
    const int h = threadIdx.x & 31;      // half2 index: batches 2h, 2h+1 of this 64-tile
    const int v = threadIdx.x >> 5;      // pixel sub-row 0..7
    half2_t* Xt2 = (half2_t*)Xt;
    #pragma unroll
    for (int pass = 0; pass < 8; ++pass) {
        int pl = pass * 8 + v;
        int p  = pt * 64 + pl;
        int r  = p >> 6, c = p & 63;
        half2_t val;
        val.x = (_Float16)T[(2 * h) * 65 + pl];
        val.y = (_Float16)T[(2 * h + 1) * 65 + pl];
        // batch b = bt*64 + 2h -> slice bg = bt>>1, half2 idx (bt&1)*32 + h
        Xt2[((size_t)(bt >> 1) * 4900 + (size_t)(r + 3) * PAD_DIM + (c + 3)) * 64
            + (bt & 1) * 32 + h] = val;
    }
}

// ---------------- main: 2 batches/lane (v_pk_fma_f32), early fold, lazy init ----------------
// Block = 4 waves = 4 filters, 128 batches (2/lane). Grid 2048: bg = bid&7 pins
// the XCD slice. acc row y is first WRITTEN at window row wr==y (lazy init, no
// pre-zero) and folds into pmax at wr==y+4 -> peak live acc rows = 5 (~60 VGPR).

#define LOAD_ROW(buf, WR) do {                                                  \
    const half2_t* rp_ = Xg + (size_t)((si + (WR)) * PAD_DIM + sj) * 64;        \
    _Pragma("unroll")                                                           \
    for (int wc = 0; wc < 10; ++wc) buf[wc] = rp_[wc * 64];                     \
} while (0)

#define COMPUTE_ROW(buf, WR) do {                                               \
    fvec2 in_[10];                                                              \
    _Pragma("unroll")                                                           \
    for (int wc = 0; wc < 10; ++wc) {                                           \
        in_[wc].x = (float)buf[wc].x;                                           \
        in_[wc].y = (float)buf[wc].y;                                           \
    }                                                                           \
    _Pragma("unroll")                                                           \
    for (int y = 0; y < 6; ++y) {                                               \
        if (y >= (((WR) > 4) ? ((WR) - 4) : 0) && y <= (WR)) {                  \
            _Pragma("unroll")                                                   \
            for (int x = 0; x < 6; ++x) {                                       \
                if (y == (WR)) {            /* first touch: kernel row 0 */     \
                    fvec2 s_ = wk[0] * in_[x];                                  \
                    _Pragma("unroll")                                           \
                    for (int c = 1; c < 5; ++c) s_ = wk[c] * in_[x + c] + s_;   \
                    acc[y * 6 + x] = s_;                                        \
                } else {                                                        \
                    const int rr = (WR) - y;                                    \
                    fvec2 s_ = acc[y * 6 + x];                                  \
                    _Pragma("unroll")                                           \
                    for (int c = 0; c < 5; ++c)                                 \
                        s_ = wk[rr * 5 + c] * in_[x + c] + s_;                  \
                    acc[y * 6 + x] = s_;                                        \
                }                                                               \
            }                                                                   \
        }                                                                       \
    }                                                                           \
    if ((WR) >= 4) {                        /* conv row fy is complete: fold */ \
        const int fy = (WR) - 4;                                                \
        _Pragma("unroll")                                                       \
        for (int px = 0; px < 2; ++px) {                                        \
            fvec2 a0 = acc[fy * 6 + 3 * px];                                    \
            fvec2 a1 = acc[fy * 6 + 3 * px + 1];                                \
            fvec2 a2 = acc[fy * 6 + 3 * px + 2];                                \
            fvec2 m_;                                                           \
            m_.x = fmaxf(fmaxf(a0.x, a1.x), a2.x);                              \
            m_.y = fmaxf(fmaxf(a0.y, a1.y), a2.y);                              \
            const int pi = ((fy >= 3) ? 2 : 0) + px;                            \
            if (fy == 0 || fy == 3) {       /* fresh pool cell, no init */      \
                pmax[pi] = m_;                                                  \
            } else {                                                            \
                pmax[pi].x = fmaxf(pmax[pi].x, m_.x);                           \
                pmax[pi].y = fmaxf(pmax[pi].y, m_.y);                           \
            }                                                                   \
        }                                                                       \
    }                                                                           \
} while (0)

__global__ __launch_bounds__(256) void filters_main(
    const half2_t* __restrict__ Xt2,   // [8 bg][4900 px][64 half2]
    const float*   __restrict__ W,     // [F][25]
    const float*   __restrict__ bias,  // [F]
    const int*     __restrict__ pos,   // [F][2]
    float4*        __restrict__ out4)  // [B][1024 float4]  (= [B][F*4] floats)
{
    const int t    = threadIdx.x;
    const int lane = t & 63;
    const int w    = t >> 6;                       // wave id 0..3
    const int bg   = blockIdx.x & 7;               // batch group (128 b) = XCD pin
    const int fg   = blockIdx.x >> 3;              // filter group (4 filters)

    const int f  = fg * 4 + w;
    const int sf = __builtin_amdgcn_readfirstlane(f);
    const int si = __builtin_amdgcn_readfirstlane(pos[2 * sf]);       // row i, 0..59
    const int sj = __builtin_amdgcn_readfirstlane(pos[2 * sf + 1]);   // col j, 0..59

    float wk[25];
    const float* wp = W + sf * 25;                 // scalar address -> s_load into SGPRs
    #pragma unroll
    for (int k = 0; k < 25; ++k) wk[k] = wp[k];

    // lane handles batches (2*lane, 2*lane+1) of slice bg: half2 index = lane
    const half2_t* Xg = Xt2 + (size_t)bg * (4900ull * 64) + lane;

    fvec2 acc[36];    // lazily initialized; peak live = 5 rows (30 fvec2)
    fvec2 pmax[4];    // lazily initialized at fy==0 / fy==3

    half2_t bufA[10], bufB[10];
    LOAD_ROW(bufA, 0);
    LOAD_ROW(bufB, 1);  COMPUTE_ROW(bufA, 0);
    LOAD_ROW(bufA, 2);  COMPUTE_ROW(bufB, 1);
    LOAD_ROW(bufB, 3);  COMPUTE_ROW(bufA, 2);
    LOAD_ROW(bufA, 4);  COMPUTE_ROW(bufB, 3);
    LOAD_ROW(bufB, 5);  COMPUTE_ROW(bufA, 4);
    LOAD_ROW(bufA, 6);  COMPUTE_ROW(bufB, 5);
    LOAD_ROW(bufB, 7);  COMPUTE_ROW(bufA, 6);
    LOAD_ROW(bufA, 8);  COMPUTE_ROW(bufB, 7);
    LOAD_ROW(bufB, 9);  COMPUTE_ROW(bufA, 8);
                        COMPUTE_ROW(bufB, 9);

    // ---- epilogue: merge 4 waves' outputs into full 64 B stores via LDS ----
    const float bv = bias[sf];
    __shared__ float S[4][128][5];                 // batch stride 5 -> 4-way max
    #pragma unroll
    for (int k = 0; k < 4; ++k) {
        S[w][2 * lane][k]     = pmax[k].x + bv;
        S[w][2 * lane + 1][k] = pmax[k].y + bv;
    }
    __syncthreads();

    // thread t -> filter-sub q = t&3, batch r0 = t>>2 (+64 on 2nd pass);
    // 4 consecutive lanes write one contiguous 64 B line out[b][fg*16..+15].
    const int q = t & 3, r0 = t >> 2;
    #pragma unroll
    for (int half = 0; half < 2; ++half) {
        const int b = r0 + half * 64;
        float4 val;
        val.x = S[q][b][0];
        val.y = S[q][b][1];
        val.z = S[q][b][2];
        val.w = S[q][b][3];
        out4[(size_t)(bg * 128 + b) * 1024 + fg * 4 + q] = val;
    }
}

extern "C" void kernel_launch(void* const* d_in, const int* in_sizes, int n_in,
                              void* d_out, int out_size, void* d_ws, size_t ws_size,
                              hipStream_t stream) {
    const float* X    = (const float*)d_in[0];
    const float* W    = (const float*)d_in[1];
    const float* bias = (const float*)d_in[2];
    const int*   pos  = (const int*)d_in[3];
    float4* out4 = (float4*)d_out;
    _Float16* Xt = (_Float16*)d_ws;        // 8*4900*128 fp16 = 10 MB

    prep_kernel<<<1024 + 804, 256, 0, stream>>>(X, Xt);
    filters_main<<<2048, 256, 0, stream>>>((const half2_t*)Xt, W, bias, pos, out4);
}